// Round 4
// baseline (813.927 us; speedup 1.0000x reference)
//
#include <hip/hip_runtime.h>
#include <hip/hip_bf16.h>

#define E_ 8
#define H_ 2048
#define I_ 1408
#define S_ 2048       // B*S tokens
#define NPAIR 4096    // S_*K
#define MAXMT 32      // worst-case M-tiles per expert (4096/128)

typedef short bf16x8 __attribute__((ext_vector_type(8)));
typedef ushort u16x8 __attribute__((ext_vector_type(8)));
typedef float f32x4  __attribute__((ext_vector_type(4)));

__device__ inline bf16x8 pack8(float4 a, float4 b) {
    bf16x8 r;
    const float v[8] = {a.x, a.y, a.z, a.w, b.x, b.y, b.z, b.w};
#pragma unroll
    for (int j = 0; j < 8; ++j) {
        __hip_bfloat16 t = __float2bfloat16(v[j]);
        r[j] = *reinterpret_cast<short*>(&t);
    }
    return r;
}

// ---------------------------------------------------------------- router ----
__global__ void moe_router(const int* __restrict__ idx,
                           int* __restrict__ counts, int* __restrict__ bases,
                           int* __restrict__ tok, int* __restrict__ inv) {
    __shared__ int cnt[E_];
    __shared__ int cur[E_];
    const int tid = threadIdx.x;
    if (tid < E_) cnt[tid] = 0;
    __syncthreads();
    for (int p = tid; p < NPAIR; p += 256)
        atomicAdd(&cnt[idx[p]], 1);
    __syncthreads();
    if (tid == 0) {
        int b = 0;
        for (int e = 0; e < E_; ++e) {
            counts[e] = cnt[e];
            bases[e]  = b;
            cur[e]    = b;
            b += cnt[e];
        }
    }
    __syncthreads();
    for (int p = tid; p < NPAIR; p += 256) {
        const int e = idx[p];
        const int pos = atomicAdd(&cur[e], 1);
        tok[pos] = p >> 1;   // token id (K=2)
        inv[p]   = pos;      // pair -> sorted position
    }
}

// ------------------------------------------------------------- convert x ----
__global__ void convert_x(const float* __restrict__ x, ushort* __restrict__ xb) {
    const size_t i = ((size_t)blockIdx.x * 256 + threadIdx.x) * 8;
    const float4 a = *(const float4*)(x + i);
    const float4 b = *(const float4*)(x + i + 4);
    *(bf16x8*)(xb + i) = pack8(a, b);
}

// ----------------------------------------------------------------- GEMM1 ----
// LDS-free K-loop: fragments loaded global->VGPR directly (A bf16 from xb,
// B fp32 from gate_up with VALU cvt). Tile 128M x 64N computing gate AND up
// for those 64 cols; fused SiLU -> h bf16 via LDS-transpose epilogue.
__global__ __launch_bounds__(256, 3)
void moe_gemm1(const ushort* __restrict__ xb,
               const float* __restrict__ wg,
               const int* __restrict__ counts,
               const int* __restrict__ bases,
               const int* __restrict__ tok,
               ushort* __restrict__ hbuf) {
    const int e  = blockIdx.y & (E_ - 1);
    const int mt = blockIdx.y >> 3;          // e fastest: same-B blocks 176 ids apart (same XCD)
    const int count = counts[e];
    if (mt * 128 >= count) return;
    const int base = bases[e];
    const int n0 = blockIdx.x * 64;
    const float* wge = wg + (size_t)e * (2 * I_) * H_;

    const int tid  = threadIdx.x;
    const int lane = tid & 63;
    const int wid  = tid >> 6;
    const int wm = wid & 1, wn = wid >> 1;
    const int lr = lane & 15, lq = lane >> 4;

    // A fragment base offsets (elements into xb), one per mi
    int aoff[4];
#pragma unroll
    for (int mi = 0; mi < 4; ++mi) {
        const int i = mt * 128 + wm * 64 + mi * 16 + lr;
        const int ic = i < count ? i : count - 1;
        aoff[mi] = tok[base + ic] * H_ + lq * 8;
    }
    // B fragment base offsets (elements into wge): f = gu*2 + ni
    int boff[4];
#pragma unroll
    for (int gu = 0; gu < 2; ++gu)
#pragma unroll
        for (int ni = 0; ni < 2; ++ni) {
            const int row = gu * I_ + n0 + wn * 32 + ni * 16 + lr;
            boff[gu * 2 + ni] = row * H_ + lq * 8;
        }

    const f32x4 vzero = {0.f, 0.f, 0.f, 0.f};
    f32x4 acc[4][4];                 // [f][mi]
#pragma unroll
    for (int f = 0; f < 4; ++f)
#pragma unroll
        for (int mi = 0; mi < 4; ++mi) acc[f][mi] = vzero;

    bf16x8 a[4], b[4];
    float4 bf[4][2];

    // prologue: kt = 0 loads
#pragma unroll
    for (int mi = 0; mi < 4; ++mi) a[mi] = *(const bf16x8*)(xb + aoff[mi]);
#pragma unroll
    for (int f = 0; f < 4; ++f) {
        bf[f][0] = *(const float4*)(wge + boff[f]);
        bf[f][1] = *(const float4*)(wge + boff[f] + 4);
    }

#pragma unroll 1
    for (int kt = 0; kt < H_ / 32 - 1; ++kt) {
        // convert current B (waits on B loads)
#pragma unroll
        for (int f = 0; f < 4; ++f) b[f] = pack8(bf[f][0], bf[f][1]);
        // issue B loads for kt+1 (regs free after cvt)
        const float* bp = wge + (kt + 1) * 32;
#pragma unroll
        for (int f = 0; f < 4; ++f) {
            bf[f][0] = *(const float4*)(bp + boff[f]);
            bf[f][1] = *(const float4*)(bp + boff[f] + 4);
        }
        // MFMAs for kt
#pragma unroll
        for (int f = 0; f < 4; ++f)
#pragma unroll
            for (int mi = 0; mi < 4; ++mi)
                acc[f][mi] = __builtin_amdgcn_mfma_f32_16x16x32_bf16(a[mi], b[f], acc[f][mi], 0, 0, 0);
        // issue A loads for kt+1
        const ushort* ap = xb + (kt + 1) * 32;
#pragma unroll
        for (int mi = 0; mi < 4; ++mi) a[mi] = *(const bf16x8*)(ap + aoff[mi]);
    }
    // last iteration
#pragma unroll
    for (int f = 0; f < 4; ++f) b[f] = pack8(bf[f][0], bf[f][1]);
#pragma unroll
    for (int f = 0; f < 4; ++f)
#pragma unroll
        for (int mi = 0; mi < 4; ++mi)
            acc[f][mi] = __builtin_amdgcn_mfma_f32_16x16x32_bf16(a[mi], b[f], acc[f][mi], 0, 0, 0);

    // epilogue: silu(g)*u -> bf16 LDS tile (128 x 64, stride 72) -> coalesced
    __shared__ alignas(16) ushort Ht[128 * 72];
#pragma unroll
    for (int mi = 0; mi < 4; ++mi)
#pragma unroll
        for (int r = 0; r < 4; ++r) {
            const int row = wm * 64 + mi * 16 + lq * 4 + r;
#pragma unroll
            for (int ni = 0; ni < 2; ++ni) {
                const int col = wn * 32 + ni * 16 + lr;
                const float g = acc[ni][mi][r];
                const float u = acc[2 + ni][mi][r];
                const float h = (g / (1.0f + __expf(-g))) * u;
                __hip_bfloat16 hb = __float2bfloat16(h);
                Ht[row * 72 + col] = *reinterpret_cast<ushort*>(&hb);
            }
        }
    __syncthreads();
#pragma unroll
    for (int p = 0; p < 4; ++p) {
        const int slot = p * 256 + tid;     // 1024 slots = 128 rows x 8 chunks
        const int row = slot >> 3;
        const int cc  = (slot & 7) * 8;
        const int gi = mt * 128 + row;
        if (gi < count)
            *(uint4*)&hbuf[(size_t)(base + gi) * I_ + n0 + cc] = *(const uint4*)&Ht[row * 72 + cc];
    }
}

// ----------------------------------------------------------------- GEMM2 ----
// LDS-free K-loop: h (bf16) @ down[e]^T (fp32, VALU cvt). Tile 128 x 128.
__global__ __launch_bounds__(256, 3)
void moe_gemm2(const ushort* __restrict__ hbuf,
               const float* __restrict__ wd,
               const int* __restrict__ counts,
               const int* __restrict__ bases,
               ushort* __restrict__ ybuf) {
    const int e  = blockIdx.y & (E_ - 1);
    const int mt = blockIdx.y >> 3;
    const int count = counts[e];
    if (mt * 128 >= count) return;
    const int base = bases[e];
    const int n0 = blockIdx.x * 128;
    const float* wde = wd + (size_t)e * H_ * I_;

    const int tid  = threadIdx.x;
    const int lane = tid & 63;
    const int wid  = tid >> 6;
    const int wm = wid & 1, wn = wid >> 1;
    const int lr = lane & 15, lq = lane >> 4;

    int aoff[4];
#pragma unroll
    for (int mi = 0; mi < 4; ++mi) {
        const int i = mt * 128 + wm * 64 + mi * 16 + lr;
        const int ic = i < count ? i : count - 1;
        aoff[mi] = (base + ic) * I_ + lq * 8;
    }
    int boff[4];
#pragma unroll
    for (int ni = 0; ni < 4; ++ni) {
        const int row = n0 + wn * 64 + ni * 16 + lr;
        boff[ni] = row * I_ + lq * 8;
    }

    const f32x4 vzero = {0.f, 0.f, 0.f, 0.f};
    f32x4 acc[4][4];                 // [ni][mi]
#pragma unroll
    for (int ni = 0; ni < 4; ++ni)
#pragma unroll
        for (int mi = 0; mi < 4; ++mi) acc[ni][mi] = vzero;

    bf16x8 a[4], b[4];
    float4 bf[4][2];

#pragma unroll
    for (int mi = 0; mi < 4; ++mi) a[mi] = *(const bf16x8*)(hbuf + aoff[mi]);
#pragma unroll
    for (int ni = 0; ni < 4; ++ni) {
        bf[ni][0] = *(const float4*)(wde + boff[ni]);
        bf[ni][1] = *(const float4*)(wde + boff[ni] + 4);
    }

#pragma unroll 1
    for (int kt = 0; kt < I_ / 32 - 1; ++kt) {
#pragma unroll
        for (int ni = 0; ni < 4; ++ni) b[ni] = pack8(bf[ni][0], bf[ni][1]);
        const float* bp = wde + (kt + 1) * 32;
#pragma unroll
        for (int ni = 0; ni < 4; ++ni) {
            bf[ni][0] = *(const float4*)(bp + boff[ni]);
            bf[ni][1] = *(const float4*)(bp + boff[ni] + 4);
        }
#pragma unroll
        for (int ni = 0; ni < 4; ++ni)
#pragma unroll
            for (int mi = 0; mi < 4; ++mi)
                acc[ni][mi] = __builtin_amdgcn_mfma_f32_16x16x32_bf16(a[mi], b[ni], acc[ni][mi], 0, 0, 0);
        const ushort* ap = hbuf + (kt + 1) * 32;
#pragma unroll
        for (int mi = 0; mi < 4; ++mi) a[mi] = *(const bf16x8*)(ap + aoff[mi]);
    }
#pragma unroll
    for (int ni = 0; ni < 4; ++ni) b[ni] = pack8(bf[ni][0], bf[ni][1]);
#pragma unroll
    for (int ni = 0; ni < 4; ++ni)
#pragma unroll
        for (int mi = 0; mi < 4; ++mi)
            acc[ni][mi] = __builtin_amdgcn_mfma_f32_16x16x32_bf16(a[mi], b[ni], acc[ni][mi], 0, 0, 0);

    // epilogue: y -> bf16 LDS tile (128 x 128, stride 136) -> coalesced
    __shared__ alignas(16) ushort Yt[128 * 136];
#pragma unroll
    for (int mi = 0; mi < 4; ++mi)
#pragma unroll
        for (int r = 0; r < 4; ++r) {
            const int row = wm * 64 + mi * 16 + lq * 4 + r;
#pragma unroll
            for (int ni = 0; ni < 4; ++ni) {
                const int col = wn * 64 + ni * 16 + lr;
                __hip_bfloat16 yb = __float2bfloat16(acc[ni][mi][r]);
                Yt[row * 136 + col] = *reinterpret_cast<ushort*>(&yb);
            }
        }
    __syncthreads();
#pragma unroll
    for (int p = 0; p < 8; ++p) {
        const int slot = p * 256 + tid;     // 2048 slots = 128 rows x 16 chunks
        const int row = slot >> 4;
        const int cc  = (slot & 15) * 8;
        const int gi = mt * 128 + row;
        if (gi < count)
            *(uint4*)&ybuf[(size_t)(base + gi) * H_ + n0 + cc] = *(const uint4*)&Yt[row * 136 + cc];
    }
}

// --------------------------------------------------------------- combine ----
__global__ void moe_combine(const ushort* __restrict__ ybuf,
                            const int* __restrict__ inv,
                            const float* __restrict__ tkw,
                            float* __restrict__ out) {
    const int t = blockIdx.x;
    const int c8 = threadIdx.x * 8;
    const int p0 = inv[2 * t], p1 = inv[2 * t + 1];
    const float w0 = tkw[2 * t], w1 = tkw[2 * t + 1];
    const u16x8 y0 = *(const u16x8*)(ybuf + (size_t)p0 * H_ + c8);
    const u16x8 y1 = *(const u16x8*)(ybuf + (size_t)p1 * H_ + c8);
    float o[8];
#pragma unroll
    for (int j = 0; j < 8; ++j) {
        const unsigned f0 = ((unsigned)y0[j]) << 16;
        const unsigned f1 = ((unsigned)y1[j]) << 16;
        o[j] = w0 * __uint_as_float(f0) + w1 * __uint_as_float(f1);
    }
    float* dst = out + (size_t)t * H_ + c8;
    *(float4*)dst       = make_float4(o[0], o[1], o[2], o[3]);
    *(float4*)(dst + 4) = make_float4(o[4], o[5], o[6], o[7]);
}

// ---------------------------------------------------------------- launch ----
extern "C" void kernel_launch(void* const* d_in, const int* in_sizes, int n_in,
                              void* d_out, int out_size, void* d_ws, size_t ws_size,
                              hipStream_t stream) {
    const float* x   = (const float*)d_in[0];
    const int*   tki = (const int*)d_in[1];
    const float* tkw = (const float*)d_in[2];
    const float* wg  = (const float*)d_in[3];
    const float* wd  = (const float*)d_in[4];
    float* out = (float*)d_out;

    char* p = (char*)d_ws;
    int* counts = (int*)p;  p += 32;
    int* bases  = (int*)p;  p += 32;
    int* tok    = (int*)p;  p += NPAIR * sizeof(int);
    int* inv    = (int*)p;  p += NPAIR * sizeof(int);
    ushort* xb   = (ushort*)p; p += (size_t)S_ * H_ * 2;       // 8 MB
    ushort* hbuf = (ushort*)p; p += (size_t)NPAIR * I_ * 2;    // 11.5 MB
    ushort* ybuf = (ushort*)p; p += (size_t)NPAIR * H_ * 2;    // 16.8 MB

    convert_x<<<dim3((S_ * H_) / (256 * 8)), 256, 0, stream>>>(x, xb);
    moe_router<<<dim3(1), 256, 0, stream>>>(tki, counts, bases, tok, inv);
    moe_gemm1<<<dim3(I_ / 64, E_ * MAXMT), 256, 0, stream>>>(xb, wg, counts, bases, tok, hbuf);
    moe_gemm2<<<dim3(H_ / 128, E_ * MAXMT), 256, 0, stream>>>(hbuf, wd, counts, bases, ybuf);
    moe_combine<<<dim3(S_), 256, 0, stream>>>(ybuf, inv, tkw, out);
}